// Round 6
// baseline (591.181 us; speedup 1.0000x reference)
//
#include <hip/hip_runtime.h>
#include <hip/hip_bf16.h>
#include <hip/hip_fp16.h>

#define N_NODES 50000
#define N_EDGES 500000
#define F_DIM   128
#define N_REL   8
#define N_LAYERS 2
#define NEG_SLOPE 0.2f

#define NBLK_N ((N_NODES + 255) / 256)   // 196 blocks over nodes

typedef short bf16x8 __attribute__((ext_vector_type(8)));
typedef float f32x4  __attribute__((ext_vector_type(4)));

// ---------------- helpers ----------------

__device__ inline short bfbits(float x) {
    __hip_bfloat16 h = __float2bfloat16(x);
    return *reinterpret_cast<short*>(&h);
}
__device__ inline float bf2f(short s) {
    unsigned u = ((unsigned)(unsigned short)s) << 16;
    return __uint_as_float(u);
}
__device__ inline float lrelu(float l) { return (l > 0.f) ? l : NEG_SLOPE * l; }

// ---------------- H prep: fp32 [N,128] -> Hh/Hl bf16 split (row-major) ------
__global__ __launch_bounds__(256) void prep_h(const float* __restrict__ H,
                                              short* __restrict__ Hh,
                                              short* __restrict__ Hl) {
    const size_t i8 = (size_t)blockIdx.x * 256 + threadIdx.x;   // 8-elem group
    if (i8 >= (size_t)N_NODES * F_DIM / 8) return;
    const float* src = H + i8 * 8;
    float av[8];
    *(float4*)(av)     = *(const float4*)(src);
    *(float4*)(av + 4) = *(const float4*)(src + 4);
    short hb[8], lb[8];
#pragma unroll
    for (int j = 0; j < 8; ++j) {
        short h = bfbits(av[j]);
        hb[j] = h;
        lb[j] = bfbits(av[j] - bf2f(h));
    }
    *(uint4*)(Hh + i8 * 8) = *(const uint4*)hb;
    *(uint4*)(Hl + i8 * 8) = *(const uint4*)lb;
}

// ---------------- W prep: W[l,r,f,g] fp32 -> Wh/Wl[l,r,g,f] bf16 split -------
__global__ __launch_bounds__(256) void prep_w(const float* __restrict__ W,
                                              short* __restrict__ Wh,
                                              short* __restrict__ Wl) {
    __shared__ float tile[64][F_DIM + 1];
    const int mat = blockIdx.x;                      // l*N_REL + r
    const float* src = W + (size_t)mat * F_DIM * F_DIM;
    const int t = threadIdx.x;
    for (int hf = 0; hf < 2; ++hf) {
#pragma unroll
        for (int i = 0; i < 8; ++i) {
            int idx = t + i * 256;
            int f = idx >> 5, c4 = idx & 31;
            float4 v = *(const float4*)(src + (size_t)(hf * 64 + f) * F_DIM + c4 * 4);
            *(float4*)&tile[f][c4 * 4] = v;
        }
        __syncthreads();
        int g = t >> 1, fs = (t & 1) * 32;
        for (int c = 0; c < 4; ++c) {
            short th[8], tl[8];
#pragma unroll
            for (int j = 0; j < 8; ++j) {
                float x = tile[fs + c * 8 + j][g];
                short hb = bfbits(x);
                th[j] = hb;
                tl[j] = bfbits(x - bf2f(hb));
            }
            size_t o = ((size_t)mat * F_DIM + g) * F_DIM + hf * 64 + fs + c * 8;
            *(uint4*)(Wh + o) = *(const uint4*)th;
            *(uint4*)(Wl + o) = *(const uint4*)tl;
        }
        __syncthreads();
    }
}

// ---------------- wq[l,r,f] = sum_g W[l,r,f,g]*q[l,g]  (and wk) -------------
__global__ __launch_bounds__(128) void prep_qk(const float* __restrict__ W,
                                               const float* __restrict__ qa,
                                               const float* __restrict__ ka,
                                               float* __restrict__ wq,
                                               float* __restrict__ wk) {
    const int mat = blockIdx.x;          // l*N_REL + r
    const int l = mat >> 3;
    const int f = threadIdx.x;           // 128
    const float* w  = W + (size_t)mat * F_DIM * F_DIM + (size_t)f * F_DIM;
    const float* qv = qa + l * F_DIM;
    const float* kv = ka + l * F_DIM;
    float sq = 0.f, sk = 0.f;
#pragma unroll
    for (int g = 0; g < F_DIM; g += 4) {
        float4 wv = *(const float4*)(w + g);
        float4 q4 = *(const float4*)(qv + g);
        float4 k4 = *(const float4*)(kv + g);
        sq += wv.x * q4.x + wv.y * q4.y + wv.z * q4.z + wv.w * q4.w;
        sk += wv.x * k4.x + wv.y * k4.y + wv.z * k4.z + wv.w * k4.w;
    }
    wq[mat * F_DIM + f] = sq;
    wk[mat * F_DIM + f] = sk;
}

// ---------------- B-stationary MFMA GEMM (pre-split A, full unroll) ---------
// grid (196, 8). Block: 256 rows of one relation. Wave w pins cols w*32..+31
// of split-W in regs (loaded once), streams 8x 32-row tiles. dt fully unrolled
// so B stays register-resident and A-loads pipeline under MFMAs.
#define ROWS_PER_BLOCK 256
__global__ __launch_bounds__(256, 2) void gemm_xw(const short* __restrict__ Hh,
                                                  const short* __restrict__ Hl,
                                                  const short* __restrict__ Wh,
                                                  const short* __restrict__ Wl,
                                                  __half* __restrict__ xw) {
    const int r   = blockIdx.y;
    const int rb0 = blockIdx.x * ROWS_PER_BLOCK;
    const int tid = threadIdx.x;
    const int lane = tid & 63, w = tid >> 6;
    const int q = lane >> 4, ln = lane & 15;

    const short* wh = Wh + (size_t)r * F_DIM * F_DIM;
    const short* wl = Wl + (size_t)r * F_DIM * F_DIM;

    // stationary B: col-tile t covers cols (w*2+t)*16..+15
    bf16x8 Bh[2][4], Bl[2][4];
#pragma unroll
    for (int t = 0; t < 2; ++t)
#pragma unroll
        for (int ks = 0; ks < 4; ++ks) {
            size_t bo = (size_t)((w * 2 + t) * 16 + ln) * F_DIM + ks * 32 + q * 8;
            Bh[t][ks] = *(const bf16x8*)(wh + bo);
            Bl[t][ks] = *(const bf16x8*)(wl + bo);
        }

#pragma unroll
    for (int dt = 0; dt < ROWS_PER_BLOCK / 32; ++dt) {
        const int rb = rb0 + dt * 32;
        bf16x8 Ah[2][4], Al[2][4];
#pragma unroll
        for (int rt = 0; rt < 2; ++rt) {
            int row = rb + rt * 16 + ln;
            int ar = (row < N_NODES) ? row : (N_NODES - 1);
            const short* hph = Hh + (size_t)ar * F_DIM;
            const short* hpl = Hl + (size_t)ar * F_DIM;
#pragma unroll
            for (int ks = 0; ks < 4; ++ks) {
                Ah[rt][ks] = *(const bf16x8*)(hph + ks * 32 + q * 8);
                Al[rt][ks] = *(const bf16x8*)(hpl + ks * 32 + q * 8);
            }
        }

        f32x4 acc[4];   // c = rt*2 + t
#pragma unroll
        for (int c = 0; c < 4; ++c) acc[c] = (f32x4)(0.f);
#pragma unroll
        for (int ks = 0; ks < 4; ++ks) {
#pragma unroll
            for (int c = 0; c < 4; ++c)
                acc[c] = __builtin_amdgcn_mfma_f32_16x16x32_bf16(Ah[c >> 1][ks], Bh[c & 1][ks], acc[c], 0, 0, 0);
#pragma unroll
            for (int c = 0; c < 4; ++c)
                acc[c] = __builtin_amdgcn_mfma_f32_16x16x32_bf16(Ah[c >> 1][ks], Bl[c & 1][ks], acc[c], 0, 0, 0);
#pragma unroll
            for (int c = 0; c < 4; ++c)
                acc[c] = __builtin_amdgcn_mfma_f32_16x16x32_bf16(Al[c >> 1][ks], Bh[c & 1][ks], acc[c], 0, 0, 0);
        }

        // store fp16: row = rb + rt*16 + q*4 + reg, col = (w*2+t)*16 + ln
#pragma unroll
        for (int c = 0; c < 4; ++c) {
            const int rt = c >> 1, t = c & 1;
            const int col = (w * 2 + t) * 16 + ln;
#pragma unroll
            for (int reg = 0; reg < 4; ++reg) {
                int row = rb + rt * 16 + q * 4 + reg;
                if (row < N_NODES)
                    xw[((size_t)r * N_NODES + row) * F_DIM + col] = __float2half(acc[c][reg]);
            }
        }
    }
}

// ---------------- a_q[r,n] = h[n].wq[r] ; a_k likewise. one wave per node ----
__global__ __launch_bounds__(256) void qk_nodes(const float* __restrict__ H,
                                                const float* __restrict__ wq,
                                                const float* __restrict__ wk,
                                                float* __restrict__ a_q,
                                                float* __restrict__ a_k) {
    const int lane = threadIdx.x & 63;
    const int wave = threadIdx.x >> 6;
    const int n = blockIdx.x * 4 + wave;
    if (n >= N_NODES) return;
    float2 h2 = *(const float2*)(H + (size_t)n * F_DIM + lane * 2);
#pragma unroll
    for (int r = 0; r < N_REL; ++r) {
        float2 q2 = *(const float2*)(wq + r * F_DIM + lane * 2);
        float2 k2 = *(const float2*)(wk + r * F_DIM + lane * 2);
        float pq = h2.x * q2.x + h2.y * q2.y;
        float pk = h2.x * k2.x + h2.y * k2.y;
#pragma unroll
        for (int off = 32; off > 0; off >>= 1) {
            pq += __shfl_xor(pq, off);
            pk += __shfl_xor(pk, off);
        }
        if (lane == 0) {
            a_q[r * N_NODES + n] = pq;
            a_k[r * N_NODES + n] = pk;
        }
    }
}

// ---------------- CSR build ----------------

__global__ __launch_bounds__(256) void count_kernel(const int* __restrict__ dstp,
                                                    int* __restrict__ cnt) {
    int e = blockIdx.x * 256 + threadIdx.x;
    if (e < N_EDGES) atomicAdd(cnt + dstp[e], 1);
}

__global__ __launch_bounds__(256) void block_sum_kernel(const int* __restrict__ cnt,
                                                        int* __restrict__ partial) {
    __shared__ int s[256];
    int idx = blockIdx.x * 256 + threadIdx.x;
    int v = (idx < N_NODES) ? cnt[idx] : 0;
    s[threadIdx.x] = v;
    __syncthreads();
    for (int off = 128; off > 0; off >>= 1) {
        if (threadIdx.x < off) s[threadIdx.x] += s[threadIdx.x + off];
        __syncthreads();
    }
    if (threadIdx.x == 0) partial[blockIdx.x] = s[0];
}

__global__ __launch_bounds__(256) void scan_partials_kernel(int* __restrict__ partial,
                                                            int* __restrict__ row_ptr) {
    __shared__ int s[256];
    int t = threadIdx.x;
    int v = (t < NBLK_N) ? partial[t] : 0;
    s[t] = v;
    __syncthreads();
#pragma unroll
    for (int off = 1; off < 256; off <<= 1) {
        int x = (t >= off) ? s[t - off] : 0;
        __syncthreads();
        s[t] += x;
        __syncthreads();
    }
    if (t < NBLK_N) partial[t] = s[t] - v;
    if (t == 0) row_ptr[N_NODES] = N_EDGES;
}

__global__ __launch_bounds__(256) void scan_block_kernel(const int* __restrict__ cnt,
                                                         const int* __restrict__ partial,
                                                         int* __restrict__ row_ptr) {
    __shared__ int s[256];
    int t = threadIdx.x;
    int idx = blockIdx.x * 256 + t;
    int v = (idx < N_NODES) ? cnt[idx] : 0;
    s[t] = v;
    __syncthreads();
#pragma unroll
    for (int off = 1; off < 256; off <<= 1) {
        int x = (t >= off) ? s[t - off] : 0;
        __syncthreads();
        s[t] += x;
        __syncthreads();
    }
    if (idx < N_NODES) row_ptr[idx] = partial[blockIdx.x] + s[t] - v;
}

__global__ __launch_bounds__(256) void scatter_kernel(const int* __restrict__ srcp,
                                                      const int* __restrict__ dstp,
                                                      const int* __restrict__ etp,
                                                      const int* __restrict__ row_ptr,
                                                      int* __restrict__ cursor,
                                                      unsigned* __restrict__ sorted) {
    int e = blockIdx.x * 256 + threadIdx.x;
    if (e >= N_EDGES) return;
    int d = dstp[e];
    int pos = atomicAdd(cursor + d, 1);
    sorted[row_ptr[d] + pos] = (unsigned)srcp[e] | ((unsigned)etp[e] << 16);
}

// ---------------- fused softmax + aggregate + bias + relu ----------------
__device__ inline float2 ldxw(const __half* xw, unsigned p, int lane) {
    const __half2 h2 = *((const __half2*)xw + (((size_t)(p >> 16)) * N_NODES + (p & 0xffff)) * (F_DIM / 2) + lane);
    return make_float2(__half2float(h2.x), __half2float(h2.y));
}

__global__ __launch_bounds__(256) void agg_fused(const __half* __restrict__ xw,
                                                 const float* __restrict__ a_q,
                                                 const float* __restrict__ a_k,
                                                 const int* __restrict__ row_ptr,
                                                 const unsigned* __restrict__ sorted,
                                                 const float* __restrict__ bias,
                                                 float* __restrict__ out) {
    const int lane = threadIdx.x & 63;
    const int wave = threadIdx.x >> 6;
    const int d = blockIdx.x * 4 + wave;
    if (d >= N_NODES) return;
    const int beg = row_ptr[d], end = row_ptr[d + 1];
    const int cnt = end - beg;

    float2 acc = *(const float2*)(bias + lane * 2);

    if (cnt <= 64) {
        unsigned p = 0;
        float l = -3.4e38f;
        if (lane < cnt) {
            p = sorted[beg + lane];
            int s = p & 0xffff, t = p >> 16;
            l = lrelu(a_q[t * N_NODES + d] + a_k[t * N_NODES + s]);
        }
        float m = l;
#pragma unroll
        for (int off = 32; off > 0; off >>= 1) m = fmaxf(m, __shfl_xor(m, off));
        float ex = (lane < cnt) ? __expf(l - m) : 0.f;
        float dsum = ex;
#pragma unroll
        for (int off = 32; off > 0; off >>= 1) dsum += __shfl_xor(dsum, off);
        float alpha = ex / (dsum + 1e-16f);

        int i = 0;
        for (; i + 4 <= cnt; i += 4) {
            unsigned p0 = __shfl(p, i), p1 = __shfl(p, i + 1);
            unsigned p2 = __shfl(p, i + 2), p3 = __shfl(p, i + 3);
            float a0 = __shfl(alpha, i), a1 = __shfl(alpha, i + 1);
            float a2 = __shfl(alpha, i + 2), a3 = __shfl(alpha, i + 3);
            float2 v0 = ldxw(xw, p0, lane);
            float2 v1 = ldxw(xw, p1, lane);
            float2 v2 = ldxw(xw, p2, lane);
            float2 v3 = ldxw(xw, p3, lane);
            acc.x = fmaf(a0, v0.x, acc.x); acc.y = fmaf(a0, v0.y, acc.y);
            acc.x = fmaf(a1, v1.x, acc.x); acc.y = fmaf(a1, v1.y, acc.y);
            acc.x = fmaf(a2, v2.x, acc.x); acc.y = fmaf(a2, v2.y, acc.y);
            acc.x = fmaf(a3, v3.x, acc.x); acc.y = fmaf(a3, v3.y, acc.y);
        }
        for (; i < cnt; ++i) {
            unsigned pi = __shfl(p, i);
            float ai = __shfl(alpha, i);
            float2 v = ldxw(xw, pi, lane);
            acc.x = fmaf(ai, v.x, acc.x);
            acc.y = fmaf(ai, v.y, acc.y);
        }
    } else {
        float m = -3.4e38f;
        for (int i = beg + lane; i < end; i += 64) {
            unsigned p = sorted[i];
            int s = p & 0xffff, t = p >> 16;
            m = fmaxf(m, lrelu(a_q[t * N_NODES + d] + a_k[t * N_NODES + s]));
        }
#pragma unroll
        for (int off = 32; off > 0; off >>= 1) m = fmaxf(m, __shfl_xor(m, off));
        float dsum = 0.f;
        for (int i = beg + lane; i < end; i += 64) {
            unsigned p = sorted[i];
            int s = p & 0xffff, t = p >> 16;
            dsum += __expf(lrelu(a_q[t * N_NODES + d] + a_k[t * N_NODES + s]) - m);
        }
#pragma unroll
        for (int off = 32; off > 0; off >>= 1) dsum += __shfl_xor(dsum, off);
        const float inv = 1.f / (dsum + 1e-16f);
        for (int i = beg; i < end; ++i) {
            unsigned p = sorted[i];
            int s = p & 0xffff, t = p >> 16;
            float alpha = __expf(lrelu(a_q[t * N_NODES + d] + a_k[t * N_NODES + s]) - m) * inv;
            float2 v = ldxw(xw, p, lane);
            acc.x = fmaf(alpha, v.x, acc.x);
            acc.y = fmaf(alpha, v.y, acc.y);
        }
    }
    acc.x = fmaxf(acc.x, 0.f);
    acc.y = fmaxf(acc.y, 0.f);
    *(float2*)(out + (size_t)d * F_DIM + lane * 2) = acc;
}

// ---------------- driver ----------------

extern "C" void kernel_launch(void* const* d_in, const int* in_sizes, int n_in,
                              void* d_out, int out_size, void* d_ws, size_t ws_size,
                              hipStream_t stream) {
    const float* x     = (const float*)d_in[0];
    const float* W     = (const float*)d_in[1];
    const float* att_q = (const float*)d_in[2];
    const float* att_k = (const float*)d_in[3];
    const float* bias  = (const float*)d_in[4];
    const int* ei      = (const int*)d_in[5];
    const int* etp     = (const int*)d_in[6];
    const int* srcp = ei;
    const int* dstp = ei + N_EDGES;
    float* out = (float*)d_out;
    char* ws   = (char*)d_ws;

    size_t off = 0;
    auto alloc = [&](size_t bytes) {
        void* p = ws + off;
        off = (off + bytes + 511) & ~(size_t)511;
        return p;
    };
    __half* xw       = (__half*)alloc((size_t)N_REL * N_NODES * F_DIM * sizeof(__half));
    float* a_q       = (float*)alloc((size_t)N_REL * N_NODES * sizeof(float));
    float* a_k       = (float*)alloc((size_t)N_REL * N_NODES * sizeof(float));
    int* cnt         = (int*)alloc((size_t)N_NODES * sizeof(int));
    int* row_ptr     = (int*)alloc(((size_t)N_NODES + 1) * sizeof(int));
    int* partial     = (int*)alloc(256 * sizeof(int));
    unsigned* sorted = (unsigned*)alloc((size_t)N_EDGES * sizeof(unsigned));
    short* Wh        = (short*)alloc((size_t)N_LAYERS * N_REL * F_DIM * F_DIM * sizeof(short));
    short* Wl        = (short*)alloc((size_t)N_LAYERS * N_REL * F_DIM * F_DIM * sizeof(short));
    short* Hh        = (short*)alloc((size_t)N_NODES * F_DIM * sizeof(short));
    short* Hl        = (short*)alloc((size_t)N_NODES * F_DIM * sizeof(short));
    float* wq        = (float*)alloc((size_t)N_LAYERS * N_REL * F_DIM * sizeof(float));
    float* wk        = (float*)alloc((size_t)N_LAYERS * N_REL * F_DIM * sizeof(float));

    prep_w<<<N_LAYERS * N_REL, 256, 0, stream>>>(W, Wh, Wl);
    prep_qk<<<N_LAYERS * N_REL, 128, 0, stream>>>(W, att_q, att_k, wq, wk);
    hipMemsetAsync(cnt, 0, (size_t)N_NODES * 4, stream);
    count_kernel<<<(N_EDGES + 255) / 256, 256, 0, stream>>>(dstp, cnt);
    block_sum_kernel<<<NBLK_N, 256, 0, stream>>>(cnt, partial);
    scan_partials_kernel<<<1, 256, 0, stream>>>(partial, row_ptr);
    scan_block_kernel<<<NBLK_N, 256, 0, stream>>>(cnt, partial, row_ptr);
    hipMemsetAsync(cnt, 0, (size_t)N_NODES * 4, stream);
    scatter_kernel<<<(N_EDGES + 255) / 256, 256, 0, stream>>>(
        srcp, dstp, etp, row_ptr, cnt, sorted);

    const int grid_h = (N_NODES * F_DIM / 8 + 255) / 256;               // 3125
    const int grid_m = (N_NODES + ROWS_PER_BLOCK - 1) / ROWS_PER_BLOCK; // 196
    for (int l = 0; l < N_LAYERS; ++l) {
        const float* H = (l == 0) ? x : out;
        prep_h<<<grid_h, 256, 0, stream>>>(H, Hh, Hl);
        gemm_xw<<<dim3(grid_m, N_REL), 256, 0, stream>>>(
            Hh, Hl,
            Wh + (size_t)l * N_REL * F_DIM * F_DIM,
            Wl + (size_t)l * N_REL * F_DIM * F_DIM, xw);
        qk_nodes<<<(N_NODES + 3) / 4, 256, 0, stream>>>(
            H, wq + (size_t)l * N_REL * F_DIM, wk + (size_t)l * N_REL * F_DIM, a_q, a_k);
        agg_fused<<<(N_NODES + 3) / 4, 256, 0, stream>>>(
            xw, a_q, a_k, row_ptr, sorted, bias + l * F_DIM, out);
    }
}

// Round 7
// 507.236 us; speedup vs baseline: 1.1655x; 1.1655x over previous
//
#include <hip/hip_runtime.h>
#include <hip/hip_bf16.h>
#include <hip/hip_fp16.h>

#define N_NODES 50000
#define N_EDGES 500000
#define F_DIM   128
#define N_REL   8
#define N_LAYERS 2
#define NEG_SLOPE 0.2f

#define NBLK_N ((N_NODES + 255) / 256)   // 196 blocks over nodes

typedef short bf16x8 __attribute__((ext_vector_type(8)));
typedef float f32x4  __attribute__((ext_vector_type(4)));

// ---------------- helpers ----------------

__device__ inline short bfbits(float x) {
    __hip_bfloat16 h = __float2bfloat16(x);
    return *reinterpret_cast<short*>(&h);
}
__device__ inline float bf2f(short s) {
    unsigned u = ((unsigned)(unsigned short)s) << 16;
    return __uint_as_float(u);
}
__device__ inline float lrelu(float l) { return (l > 0.f) ? l : NEG_SLOPE * l; }
__device__ inline void atomAddF(float* p, float v) { unsafeAtomicAdd(p, v); }

// ---------------- H prep: fp32 [N,128] -> Hh/Hl bf16 split (row-major) ------
__global__ __launch_bounds__(256) void prep_h(const float* __restrict__ H,
                                              short* __restrict__ Hh,
                                              short* __restrict__ Hl) {
    const size_t i8 = (size_t)blockIdx.x * 256 + threadIdx.x;   // 8-elem group
    if (i8 >= (size_t)N_NODES * F_DIM / 8) return;
    const float* src = H + i8 * 8;
    float av[8];
    *(float4*)(av)     = *(const float4*)(src);
    *(float4*)(av + 4) = *(const float4*)(src + 4);
    short hb[8], lb[8];
#pragma unroll
    for (int j = 0; j < 8; ++j) {
        short h = bfbits(av[j]);
        hb[j] = h;
        lb[j] = bfbits(av[j] - bf2f(h));
    }
    *(uint4*)(Hh + i8 * 8) = *(const uint4*)hb;
    *(uint4*)(Hl + i8 * 8) = *(const uint4*)lb;
}

// ---------------- W prep: W[l,r,f,g] fp32 -> Wh/Wl[l,r,g,f] bf16 split -------
__global__ __launch_bounds__(256) void prep_w(const float* __restrict__ W,
                                              short* __restrict__ Wh,
                                              short* __restrict__ Wl) {
    __shared__ float tile[64][F_DIM + 1];
    const int mat = blockIdx.x;                      // l*N_REL + r
    const float* src = W + (size_t)mat * F_DIM * F_DIM;
    const int t = threadIdx.x;
    for (int hf = 0; hf < 2; ++hf) {
#pragma unroll
        for (int i = 0; i < 8; ++i) {
            int idx = t + i * 256;
            int f = idx >> 5, c4 = idx & 31;
            float4 v = *(const float4*)(src + (size_t)(hf * 64 + f) * F_DIM + c4 * 4);
            *(float4*)&tile[f][c4 * 4] = v;
        }
        __syncthreads();
        int g = t >> 1, fs = (t & 1) * 32;
        for (int c = 0; c < 4; ++c) {
            short th[8], tl[8];
#pragma unroll
            for (int j = 0; j < 8; ++j) {
                float x = tile[fs + c * 8 + j][g];
                short hb = bfbits(x);
                th[j] = hb;
                tl[j] = bfbits(x - bf2f(hb));
            }
            size_t o = ((size_t)mat * F_DIM + g) * F_DIM + hf * 64 + fs + c * 8;
            *(uint4*)(Wh + o) = *(const uint4*)th;
            *(uint4*)(Wl + o) = *(const uint4*)tl;
        }
        __syncthreads();
    }
}

// ---------------- LDS-B-stationary MFMA GEMM (+fused q/k dots) --------------
// grid (98, 8), 512 threads (8 waves). Block stages split-W of its relation
// into 64 KB LDS (XOR-swizzled, conflict-free ds_read_b128), then streams
// 512 rows. Wave w: col-tile (w&3)*32, row-half (w>>2)*32 of each 64-row dt.
#define RPB 512
__global__ __launch_bounds__(512, 2) void gemm_xw(const short* __restrict__ Hh,
                                                  const short* __restrict__ Hl,
                                                  const short* __restrict__ Wh,
                                                  const short* __restrict__ Wl,
                                                  const float* __restrict__ qv_g,
                                                  const float* __restrict__ kv_g,
                                                  __half* __restrict__ xw,
                                                  float* __restrict__ a_q,
                                                  float* __restrict__ a_k) {
    __shared__ short lds[2 * F_DIM * F_DIM];   // 65536 B: [hi|lo][col][f] swizzled
    const int r   = blockIdx.y;
    const int rb0 = blockIdx.x * RPB;
    const int tid = threadIdx.x;
    const int lane = tid & 63, w = tid >> 6;
    const int colt = w & 3, half = w >> 2;
    const int q = lane >> 4, ln = lane & 15;

    // stage W: chunk = 16B; dst chunk index XOR-swizzled by col
    {
        const short* s0 = Wh + (size_t)r * F_DIM * F_DIM;
        const short* s1 = Wl + (size_t)r * F_DIM * F_DIM;
#pragma unroll
        for (int a = 0; a < 2; ++a) {
            const short* src = a ? s1 : s0;
#pragma unroll
            for (int i = 0; i < 4; ++i) {
                int chunk = tid + i * 512;           // [0, 2048)
                int g = chunk >> 4, c8 = chunk & 15;
                uint4 v = *(const uint4*)(src + g * F_DIM + c8 * 8);
                *(uint4*)(lds + a * 16384 + g * F_DIM + ((c8 ^ (g & 15)) * 8)) = v;
            }
        }
    }
    __syncthreads();

    const int col0 = colt * 32 + ln;
    const int col1 = colt * 32 + 16 + ln;
    const float qv0 = qv_g[col0], qv1 = qv_g[col1];
    const float kv0 = kv_g[col0], kv1 = kv_g[col1];

    for (int dt = 0; dt < RPB / 64; ++dt) {
        const int rbw = rb0 + dt * 64 + half * 32;
        // A fragments: rows rbw + rt*16 + ln, from pre-split global (L1/L2 hot)
        bf16x8 Ah[2][4], Al[2][4];
#pragma unroll
        for (int rt = 0; rt < 2; ++rt) {
            int row = rbw + rt * 16 + ln;
            int ar = (row < N_NODES) ? row : (N_NODES - 1);
            const short* hph = Hh + (size_t)ar * F_DIM;
            const short* hpl = Hl + (size_t)ar * F_DIM;
#pragma unroll
            for (int ks = 0; ks < 4; ++ks) {
                Ah[rt][ks] = *(const bf16x8*)(hph + ks * 32 + q * 8);
                Al[rt][ks] = *(const bf16x8*)(hpl + ks * 32 + q * 8);
            }
        }

        f32x4 acc[4];   // c = rt*2 + t
#pragma unroll
        for (int c = 0; c < 4; ++c) acc[c] = (f32x4)(0.f);
#pragma unroll
        for (int ks = 0; ks < 4; ++ks) {
            const int j = ks * 4 + q;                 // 16B chunk index along f
            bf16x8 Bh0 = *(const bf16x8*)(lds +         col0 * F_DIM + ((j ^ (col0 & 15)) << 3));
            bf16x8 Bh1 = *(const bf16x8*)(lds +         col1 * F_DIM + ((j ^ (col1 & 15)) << 3));
            bf16x8 Bl0 = *(const bf16x8*)(lds + 16384 + col0 * F_DIM + ((j ^ (col0 & 15)) << 3));
            bf16x8 Bl1 = *(const bf16x8*)(lds + 16384 + col1 * F_DIM + ((j ^ (col1 & 15)) << 3));
            acc[0] = __builtin_amdgcn_mfma_f32_16x16x32_bf16(Ah[0][ks], Bh0, acc[0], 0, 0, 0);
            acc[1] = __builtin_amdgcn_mfma_f32_16x16x32_bf16(Ah[0][ks], Bh1, acc[1], 0, 0, 0);
            acc[2] = __builtin_amdgcn_mfma_f32_16x16x32_bf16(Ah[1][ks], Bh0, acc[2], 0, 0, 0);
            acc[3] = __builtin_amdgcn_mfma_f32_16x16x32_bf16(Ah[1][ks], Bh1, acc[3], 0, 0, 0);
            acc[0] = __builtin_amdgcn_mfma_f32_16x16x32_bf16(Ah[0][ks], Bl0, acc[0], 0, 0, 0);
            acc[1] = __builtin_amdgcn_mfma_f32_16x16x32_bf16(Ah[0][ks], Bl1, acc[1], 0, 0, 0);
            acc[2] = __builtin_amdgcn_mfma_f32_16x16x32_bf16(Ah[1][ks], Bl0, acc[2], 0, 0, 0);
            acc[3] = __builtin_amdgcn_mfma_f32_16x16x32_bf16(Ah[1][ks], Bl1, acc[3], 0, 0, 0);
            acc[0] = __builtin_amdgcn_mfma_f32_16x16x32_bf16(Al[0][ks], Bh0, acc[0], 0, 0, 0);
            acc[1] = __builtin_amdgcn_mfma_f32_16x16x32_bf16(Al[0][ks], Bh1, acc[1], 0, 0, 0);
            acc[2] = __builtin_amdgcn_mfma_f32_16x16x32_bf16(Al[1][ks], Bh0, acc[2], 0, 0, 0);
            acc[3] = __builtin_amdgcn_mfma_f32_16x16x32_bf16(Al[1][ks], Bh1, acc[3], 0, 0, 0);
        }

        // epilogue: fp16 stores + fused q/k dots (shfl-reduce over ln, atomic)
#pragma unroll
        for (int rt = 0; rt < 2; ++rt) {
            float pq[4], pk[4];
#pragma unroll
            for (int reg = 0; reg < 4; ++reg) {
                int row = rbw + rt * 16 + q * 4 + reg;
                float v0 = acc[rt * 2 + 0][reg];
                float v1 = acc[rt * 2 + 1][reg];
                if (row < N_NODES) {
                    __half* dst = xw + ((size_t)r * N_NODES + row) * F_DIM;
                    dst[col0] = __float2half(v0);
                    dst[col1] = __float2half(v1);
                }
                pq[reg] = v0 * qv0 + v1 * qv1;
                pk[reg] = v0 * kv0 + v1 * kv1;
            }
#pragma unroll
            for (int reg = 0; reg < 4; ++reg) {
#pragma unroll
                for (int m = 1; m <= 8; m <<= 1) {
                    pq[reg] += __shfl_xor(pq[reg], m);
                    pk[reg] += __shfl_xor(pk[reg], m);
                }
            }
            if (ln == 0) {
#pragma unroll
                for (int reg = 0; reg < 4; ++reg) {
                    int row = rbw + rt * 16 + q * 4 + reg;
                    if (row < N_NODES) {
                        atomAddF(a_q + r * N_NODES + row, pq[reg]);
                        atomAddF(a_k + r * N_NODES + row, pk[reg]);
                    }
                }
            }
        }
    }
}

// ---------------- CSR build ----------------

__global__ __launch_bounds__(256) void count_kernel(const int* __restrict__ dstp,
                                                    int* __restrict__ cnt) {
    int e = blockIdx.x * 256 + threadIdx.x;
    if (e < N_EDGES) atomicAdd(cnt + dstp[e], 1);
}

__global__ __launch_bounds__(256) void block_sum_kernel(const int* __restrict__ cnt,
                                                        int* __restrict__ partial) {
    __shared__ int s[256];
    int idx = blockIdx.x * 256 + threadIdx.x;
    int v = (idx < N_NODES) ? cnt[idx] : 0;
    s[threadIdx.x] = v;
    __syncthreads();
    for (int off = 128; off > 0; off >>= 1) {
        if (threadIdx.x < off) s[threadIdx.x] += s[threadIdx.x + off];
        __syncthreads();
    }
    if (threadIdx.x == 0) partial[blockIdx.x] = s[0];
}

__global__ __launch_bounds__(256) void scan_partials_kernel(int* __restrict__ partial,
                                                            int* __restrict__ row_ptr) {
    __shared__ int s[256];
    int t = threadIdx.x;
    int v = (t < NBLK_N) ? partial[t] : 0;
    s[t] = v;
    __syncthreads();
#pragma unroll
    for (int off = 1; off < 256; off <<= 1) {
        int x = (t >= off) ? s[t - off] : 0;
        __syncthreads();
        s[t] += x;
        __syncthreads();
    }
    if (t < NBLK_N) partial[t] = s[t] - v;
    if (t == 0) row_ptr[N_NODES] = N_EDGES;
}

__global__ __launch_bounds__(256) void scan_block_kernel(const int* __restrict__ cnt,
                                                         const int* __restrict__ partial,
                                                         int* __restrict__ row_ptr) {
    __shared__ int s[256];
    int t = threadIdx.x;
    int idx = blockIdx.x * 256 + t;
    int v = (idx < N_NODES) ? cnt[idx] : 0;
    s[t] = v;
    __syncthreads();
#pragma unroll
    for (int off = 1; off < 256; off <<= 1) {
        int x = (t >= off) ? s[t - off] : 0;
        __syncthreads();
        s[t] += x;
        __syncthreads();
    }
    if (idx < N_NODES) row_ptr[idx] = partial[blockIdx.x] + s[t] - v;
}

__global__ __launch_bounds__(256) void scatter_kernel(const int* __restrict__ srcp,
                                                      const int* __restrict__ dstp,
                                                      const int* __restrict__ etp,
                                                      const int* __restrict__ row_ptr,
                                                      int* __restrict__ cursor,
                                                      unsigned* __restrict__ sorted) {
    int e = blockIdx.x * 256 + threadIdx.x;
    if (e >= N_EDGES) return;
    int d = dstp[e];
    int pos = atomicAdd(cursor + d, 1);
    sorted[row_ptr[d] + pos] = (unsigned)srcp[e] | ((unsigned)etp[e] << 16);
}

// ---------------- fused softmax + aggregate + bias + relu ----------------
__device__ inline float2 ldxw(const __half* xw, unsigned p, int lane) {
    const __half2 h2 = *((const __half2*)xw + (((size_t)(p >> 16)) * N_NODES + (p & 0xffff)) * (F_DIM / 2) + lane);
    return make_float2(__half2float(h2.x), __half2float(h2.y));
}

__global__ __launch_bounds__(256) void agg_fused(const __half* __restrict__ xw,
                                                 const float* __restrict__ a_q,
                                                 const float* __restrict__ a_k,
                                                 const int* __restrict__ row_ptr,
                                                 const unsigned* __restrict__ sorted,
                                                 const float* __restrict__ bias,
                                                 float* __restrict__ out) {
    const int lane = threadIdx.x & 63;
    const int wave = threadIdx.x >> 6;
    const int d = blockIdx.x * 4 + wave;
    if (d >= N_NODES) return;
    const int beg = row_ptr[d], end = row_ptr[d + 1];
    const int cnt = end - beg;

    float2 acc = *(const float2*)(bias + lane * 2);

    if (cnt <= 64) {
        unsigned p = 0;
        float l = -3.4e38f;
        if (lane < cnt) {
            p = sorted[beg + lane];
            int s = p & 0xffff, t = p >> 16;
            l = lrelu(a_q[t * N_NODES + d] + a_k[t * N_NODES + s]);
        }
        float m = l;
#pragma unroll
        for (int off = 32; off > 0; off >>= 1) m = fmaxf(m, __shfl_xor(m, off));
        float ex = (lane < cnt) ? __expf(l - m) : 0.f;
        float dsum = ex;
#pragma unroll
        for (int off = 32; off > 0; off >>= 1) dsum += __shfl_xor(dsum, off);
        float alpha = ex / (dsum + 1e-16f);

        int i = 0;
        for (; i + 4 <= cnt; i += 4) {
            unsigned p0 = __shfl(p, i), p1 = __shfl(p, i + 1);
            unsigned p2 = __shfl(p, i + 2), p3 = __shfl(p, i + 3);
            float a0 = __shfl(alpha, i), a1 = __shfl(alpha, i + 1);
            float a2 = __shfl(alpha, i + 2), a3 = __shfl(alpha, i + 3);
            float2 v0 = ldxw(xw, p0, lane);
            float2 v1 = ldxw(xw, p1, lane);
            float2 v2 = ldxw(xw, p2, lane);
            float2 v3 = ldxw(xw, p3, lane);
            acc.x = fmaf(a0, v0.x, acc.x); acc.y = fmaf(a0, v0.y, acc.y);
            acc.x = fmaf(a1, v1.x, acc.x); acc.y = fmaf(a1, v1.y, acc.y);
            acc.x = fmaf(a2, v2.x, acc.x); acc.y = fmaf(a2, v2.y, acc.y);
            acc.x = fmaf(a3, v3.x, acc.x); acc.y = fmaf(a3, v3.y, acc.y);
        }
        for (; i < cnt; ++i) {
            unsigned pi = __shfl(p, i);
            float ai = __shfl(alpha, i);
            float2 v = ldxw(xw, pi, lane);
            acc.x = fmaf(ai, v.x, acc.x);
            acc.y = fmaf(ai, v.y, acc.y);
        }
    } else {
        float m = -3.4e38f;
        for (int i = beg + lane; i < end; i += 64) {
            unsigned p = sorted[i];
            int s = p & 0xffff, t = p >> 16;
            m = fmaxf(m, lrelu(a_q[t * N_NODES + d] + a_k[t * N_NODES + s]));
        }
#pragma unroll
        for (int off = 32; off > 0; off >>= 1) m = fmaxf(m, __shfl_xor(m, off));
        float dsum = 0.f;
        for (int i = beg + lane; i < end; i += 64) {
            unsigned p = sorted[i];
            int s = p & 0xffff, t = p >> 16;
            dsum += __expf(lrelu(a_q[t * N_NODES + d] + a_k[t * N_NODES + s]) - m);
        }
#pragma unroll
        for (int off = 32; off > 0; off >>= 1) dsum += __shfl_xor(dsum, off);
        const float inv = 1.f / (dsum + 1e-16f);
        for (int i = beg; i < end; ++i) {
            unsigned p = sorted[i];
            int s = p & 0xffff, t = p >> 16;
            float alpha = __expf(lrelu(a_q[t * N_NODES + d] + a_k[t * N_NODES + s]) - m) * inv;
            float2 v = ldxw(xw, p, lane);
            acc.x = fmaf(alpha, v.x, acc.x);
            acc.y = fmaf(alpha, v.y, acc.y);
        }
    }
    acc.x = fmaxf(acc.x, 0.f);
    acc.y = fmaxf(acc.y, 0.f);
    *(float2*)(out + (size_t)d * F_DIM + lane * 2) = acc;
}

// ---------------- driver ----------------

extern "C" void kernel_launch(void* const* d_in, const int* in_sizes, int n_in,
                              void* d_out, int out_size, void* d_ws, size_t ws_size,
                              hipStream_t stream) {
    const float* x     = (const float*)d_in[0];
    const float* W     = (const float*)d_in[1];
    const float* att_q = (const float*)d_in[2];
    const float* att_k = (const float*)d_in[3];
    const float* bias  = (const float*)d_in[4];
    const int* ei      = (const int*)d_in[5];
    const int* etp     = (const int*)d_in[6];
    const int* srcp = ei;
    const int* dstp = ei + N_EDGES;
    float* out = (float*)d_out;
    char* ws   = (char*)d_ws;

    size_t off = 0;
    auto alloc = [&](size_t bytes) {
        void* p = ws + off;
        off = (off + bytes + 511) & ~(size_t)511;
        return p;
    };
    __half* xw       = (__half*)alloc((size_t)N_REL * N_NODES * F_DIM * sizeof(__half));
    float* a_q       = (float*)alloc((size_t)N_REL * N_NODES * sizeof(float));
    float* a_k       = (float*)alloc((size_t)N_REL * N_NODES * sizeof(float));
    int* cnt         = (int*)alloc((size_t)N_NODES * sizeof(int));
    int* row_ptr     = (int*)alloc(((size_t)N_NODES + 1) * sizeof(int));
    int* partial     = (int*)alloc(256 * sizeof(int));
    unsigned* sorted = (unsigned*)alloc((size_t)N_EDGES * sizeof(unsigned));
    short* Wh        = (short*)alloc((size_t)N_LAYERS * N_REL * F_DIM * F_DIM * sizeof(short));
    short* Wl        = (short*)alloc((size_t)N_LAYERS * N_REL * F_DIM * F_DIM * sizeof(short));
    short* Hh        = (short*)alloc((size_t)N_NODES * F_DIM * sizeof(short));
    short* Hl        = (short*)alloc((size_t)N_NODES * F_DIM * sizeof(short));

    prep_w<<<N_LAYERS * N_REL, 256, 0, stream>>>(W, Wh, Wl);
    hipMemsetAsync(cnt, 0, (size_t)N_NODES * 4, stream);
    count_kernel<<<(N_EDGES + 255) / 256, 256, 0, stream>>>(dstp, cnt);
    block_sum_kernel<<<NBLK_N, 256, 0, stream>>>(cnt, partial);
    scan_partials_kernel<<<1, 256, 0, stream>>>(partial, row_ptr);
    scan_block_kernel<<<NBLK_N, 256, 0, stream>>>(cnt, partial, row_ptr);
    hipMemsetAsync(cnt, 0, (size_t)N_NODES * 4, stream);
    scatter_kernel<<<(N_EDGES + 255) / 256, 256, 0, stream>>>(
        srcp, dstp, etp, row_ptr, cnt, sorted);

    const int grid_h = (N_NODES * F_DIM / 8 + 255) / 256;   // 3125
    const int grid_m = (N_NODES + RPB - 1) / RPB;           // 98
    for (int l = 0; l < N_LAYERS; ++l) {
        const float* H = (l == 0) ? x : out;
        prep_h<<<grid_h, 256, 0, stream>>>(H, Hh, Hl);
        hipMemsetAsync(a_q, 0, (size_t)N_REL * N_NODES * 4, stream);
        hipMemsetAsync(a_k, 0, (size_t)N_REL * N_NODES * 4, stream);
        gemm_xw<<<dim3(grid_m, N_REL), 512, 0, stream>>>(
            Hh, Hl,
            Wh + (size_t)l * N_REL * F_DIM * F_DIM,
            Wl + (size_t)l * N_REL * F_DIM * F_DIM,
            att_q + l * F_DIM, att_k + l * F_DIM,
            xw, a_q, a_k);
        agg_fused<<<(N_NODES + 3) / 4, 256, 0, stream>>>(
            xw, a_q, a_k, row_ptr, sorted, bias + l * F_DIM, out);
    }
}

// Round 8
// 364.730 us; speedup vs baseline: 1.6209x; 1.3907x over previous
//
#include <hip/hip_runtime.h>
#include <hip/hip_bf16.h>
#include <hip/hip_fp16.h>

#define N_NODES 50000
#define N_EDGES 500000
#define F_DIM   128
#define N_REL   8
#define N_LAYERS 2
#define NEG_SLOPE 0.2f

#define NBLK_N ((N_NODES + 255) / 256)   // 196 blocks over nodes

typedef short bf16x8 __attribute__((ext_vector_type(8)));
typedef float f32x4  __attribute__((ext_vector_type(4)));

// ---------------- helpers ----------------

__device__ inline short bfbits(float x) {
    __hip_bfloat16 h = __float2bfloat16(x);
    return *reinterpret_cast<short*>(&h);
}
__device__ inline float bf2f(short s) {
    unsigned u = ((unsigned)(unsigned short)s) << 16;
    return __uint_as_float(u);
}
__device__ inline float lrelu(float l) { return (l > 0.f) ? l : NEG_SLOPE * l; }

// ---------------- H prep: fp32 [N,128] -> Hh/Hl bf16 split (row-major) ------
__global__ __launch_bounds__(256) void prep_h(const float* __restrict__ H,
                                              short* __restrict__ Hh,
                                              short* __restrict__ Hl) {
    const size_t i8 = (size_t)blockIdx.x * 256 + threadIdx.x;   // 8-elem group
    if (i8 >= (size_t)N_NODES * F_DIM / 8) return;
    const float* src = H + i8 * 8;
    float av[8];
    *(float4*)(av)     = *(const float4*)(src);
    *(float4*)(av + 4) = *(const float4*)(src + 4);
    short hb[8], lb[8];
#pragma unroll
    for (int j = 0; j < 8; ++j) {
        short h = bfbits(av[j]);
        hb[j] = h;
        lb[j] = bfbits(av[j] - bf2f(h));
    }
    *(uint4*)(Hh + i8 * 8) = *(const uint4*)hb;
    *(uint4*)(Hl + i8 * 8) = *(const uint4*)lb;
}

// ---------------- W prep: W[l,r,f,g] fp32 -> Wh/Wl[l,r,g,f] bf16 split -------
__global__ __launch_bounds__(256) void prep_w(const float* __restrict__ W,
                                              short* __restrict__ Wh,
                                              short* __restrict__ Wl) {
    __shared__ float tile[64][F_DIM + 1];
    const int mat = blockIdx.x;                      // l*N_REL + r
    const float* src = W + (size_t)mat * F_DIM * F_DIM;
    const int t = threadIdx.x;
    for (int hf = 0; hf < 2; ++hf) {
#pragma unroll
        for (int i = 0; i < 8; ++i) {
            int idx = t + i * 256;
            int f = idx >> 5, c4 = idx & 31;
            float4 v = *(const float4*)(src + (size_t)(hf * 64 + f) * F_DIM + c4 * 4);
            *(float4*)&tile[f][c4 * 4] = v;
        }
        __syncthreads();
        int g = t >> 1, fs = (t & 1) * 32;
        for (int c = 0; c < 4; ++c) {
            short th[8], tl[8];
#pragma unroll
            for (int j = 0; j < 8; ++j) {
                float x = tile[fs + c * 8 + j][g];
                short hb = bfbits(x);
                th[j] = hb;
                tl[j] = bfbits(x - bf2f(hb));
            }
            size_t o = ((size_t)mat * F_DIM + g) * F_DIM + hf * 64 + fs + c * 8;
            *(uint4*)(Wh + o) = *(const uint4*)th;
            *(uint4*)(Wl + o) = *(const uint4*)tl;
        }
        __syncthreads();
    }
}

// ---------------- A-stationary MFMA GEMM (+fused q/k dots, no atomics) ------
// grid (391, 2), 512 threads (8 waves). Wave w owns rows rb0 + w*16 .. +15
// with split-A pinned in VGPRs across 4 relations (blockIdx.y picks which 4).
// W cycles through 64 KB XOR-swizzled LDS. xw stored COLUMN-PERMUTED:
//   xw'[row][ln*8 + t] = C[row][t*16 + ln]   (16B uint4 stores per lane)
// agg maps position p -> col (p&7)*16 + (p>>3).
#define GBM 128
#define RGRP 4
__global__ __launch_bounds__(512, 2) void gemm_xw(const short* __restrict__ Hh,
                                                  const short* __restrict__ Hl,
                                                  const short* __restrict__ Wh,
                                                  const short* __restrict__ Wl,
                                                  const float* __restrict__ qv_g,
                                                  const float* __restrict__ kv_g,
                                                  __half* __restrict__ xw,
                                                  float* __restrict__ a_q,
                                                  float* __restrict__ a_k) {
    __shared__ short lds[2 * F_DIM * F_DIM];   // 64 KB, [hi|lo][col][f] swizzled
    const int rb0 = blockIdx.x * GBM;
    const int r0  = blockIdx.y * RGRP;
    const int tid = threadIdx.x;
    const int lane = tid & 63, w = tid >> 6;
    const int q = lane >> 4, ln = lane & 15;

    // pinned A fragments for this lane's row
    const int arow_raw = rb0 + w * 16 + ln;
    const int arow = (arow_raw < N_NODES) ? arow_raw : (N_NODES - 1);
    bf16x8 Ah[4], Al[4];
    {
        const short* hph = Hh + (size_t)arow * F_DIM;
        const short* hpl = Hl + (size_t)arow * F_DIM;
#pragma unroll
        for (int ks = 0; ks < 4; ++ks) {
            Ah[ks] = *(const bf16x8*)(hph + ks * 32 + q * 8);
            Al[ks] = *(const bf16x8*)(hpl + ks * 32 + q * 8);
        }
    }

    for (int rr = 0; rr < RGRP; ++rr) {
        const int r = r0 + rr;
        __syncthreads();   // prev-relation LDS reads done
        // stage split-W[r]: 4096 16B chunks, 8 per thread, XOR-swizzled
        {
            const short* s0 = Wh + (size_t)r * F_DIM * F_DIM;
            const short* s1 = Wl + (size_t)r * F_DIM * F_DIM;
#pragma unroll
            for (int a = 0; a < 2; ++a) {
                const short* src = a ? s1 : s0;
#pragma unroll
                for (int i = 0; i < 4; ++i) {
                    int chunk = tid + i * 512;           // [0, 2048)
                    int g = chunk >> 4, c8 = chunk & 15;
                    uint4 v = *(const uint4*)(src + g * F_DIM + c8 * 8);
                    *(uint4*)(lds + a * 16384 + g * F_DIM + ((c8 ^ (g & 15)) * 8)) = v;
                }
            }
        }
        __syncthreads();

        f32x4 acc[8];
#pragma unroll
        for (int t = 0; t < 8; ++t) acc[t] = (f32x4)(0.f);
#pragma unroll
        for (int ks = 0; ks < 4; ++ks) {
            const int j = ks * 4 + q;                    // 16B chunk index along f
            bf16x8 Bh[8], Bl[8];
#pragma unroll
            for (int t = 0; t < 8; ++t) {
                const int col = t * 16 + ln;             // col & 15 == ln
                Bh[t] = *(const bf16x8*)(lds +         col * F_DIM + ((j ^ ln) << 3));
                Bl[t] = *(const bf16x8*)(lds + 16384 + col * F_DIM + ((j ^ ln) << 3));
            }
            // 8 independent chains per pass
#pragma unroll
            for (int t = 0; t < 8; ++t)
                acc[t] = __builtin_amdgcn_mfma_f32_16x16x32_bf16(Ah[ks], Bh[t], acc[t], 0, 0, 0);
#pragma unroll
            for (int t = 0; t < 8; ++t)
                acc[t] = __builtin_amdgcn_mfma_f32_16x16x32_bf16(Ah[ks], Bl[t], acc[t], 0, 0, 0);
#pragma unroll
            for (int t = 0; t < 8; ++t)
                acc[t] = __builtin_amdgcn_mfma_f32_16x16x32_bf16(Al[ks], Bh[t], acc[t], 0, 0, 0);
        }

        // epilogue: permuted 16B stores + in-wave q/k dots (no atomics)
        float qvl[8], kvl[8];
#pragma unroll
        for (int t = 0; t < 8; ++t) {
            qvl[t] = qv_g[t * 16 + ln];
            kvl[t] = kv_g[t * 16 + ln];
        }
        float pq[4], pk[4];
#pragma unroll
        for (int reg = 0; reg < 4; ++reg) {
            const int row = rb0 + w * 16 + q * 4 + reg;
            unsigned short hs[8];
            float sq = 0.f, sk = 0.f;
#pragma unroll
            for (int t = 0; t < 8; ++t) {
                float v = acc[t][reg];
                __half hv = __float2half(v);
                hs[t] = *reinterpret_cast<unsigned short*>(&hv);
                sq = fmaf(v, qvl[t], sq);
                sk = fmaf(v, kvl[t], sk);
            }
            if (row < N_NODES)
                *(uint4*)(xw + ((size_t)r * N_NODES + row) * F_DIM + ln * 8) = *(const uint4*)hs;
            pq[reg] = sq; pk[reg] = sk;
        }
#pragma unroll
        for (int reg = 0; reg < 4; ++reg) {
#pragma unroll
            for (int m = 1; m <= 8; m <<= 1) {
                pq[reg] += __shfl_xor(pq[reg], m);
                pk[reg] += __shfl_xor(pk[reg], m);
            }
        }
        if (ln == 0) {
#pragma unroll
            for (int reg = 0; reg < 4; ++reg) {
                const int row = rb0 + w * 16 + q * 4 + reg;
                if (row < N_NODES) {
                    a_q[r * N_NODES + row] = pq[reg];
                    a_k[r * N_NODES + row] = pk[reg];
                }
            }
        }
    }
}

// ---------------- CSR build ----------------

__global__ __launch_bounds__(256) void count_kernel(const int* __restrict__ dstp,
                                                    int* __restrict__ cnt) {
    int e = blockIdx.x * 256 + threadIdx.x;
    if (e < N_EDGES) atomicAdd(cnt + dstp[e], 1);
}

__global__ __launch_bounds__(256) void block_sum_kernel(const int* __restrict__ cnt,
                                                        int* __restrict__ partial) {
    __shared__ int s[256];
    int idx = blockIdx.x * 256 + threadIdx.x;
    int v = (idx < N_NODES) ? cnt[idx] : 0;
    s[threadIdx.x] = v;
    __syncthreads();
    for (int off = 128; off > 0; off >>= 1) {
        if (threadIdx.x < off) s[threadIdx.x] += s[threadIdx.x + off];
        __syncthreads();
    }
    if (threadIdx.x == 0) partial[blockIdx.x] = s[0];
}

__global__ __launch_bounds__(256) void scan_partials_kernel(int* __restrict__ partial,
                                                            int* __restrict__ row_ptr) {
    __shared__ int s[256];
    int t = threadIdx.x;
    int v = (t < NBLK_N) ? partial[t] : 0;
    s[t] = v;
    __syncthreads();
#pragma unroll
    for (int off = 1; off < 256; off <<= 1) {
        int x = (t >= off) ? s[t - off] : 0;
        __syncthreads();
        s[t] += x;
        __syncthreads();
    }
    if (t < NBLK_N) partial[t] = s[t] - v;
    if (t == 0) row_ptr[N_NODES] = N_EDGES;
}

__global__ __launch_bounds__(256) void scan_block_kernel(const int* __restrict__ cnt,
                                                         const int* __restrict__ partial,
                                                         int* __restrict__ row_ptr) {
    __shared__ int s[256];
    int t = threadIdx.x;
    int idx = blockIdx.x * 256 + t;
    int v = (idx < N_NODES) ? cnt[idx] : 0;
    s[t] = v;
    __syncthreads();
#pragma unroll
    for (int off = 1; off < 256; off <<= 1) {
        int x = (t >= off) ? s[t - off] : 0;
        __syncthreads();
        s[t] += x;
        __syncthreads();
    }
    if (idx < N_NODES) row_ptr[idx] = partial[blockIdx.x] + s[t] - v;
}

__global__ __launch_bounds__(256) void scatter_kernel(const int* __restrict__ srcp,
                                                      const int* __restrict__ dstp,
                                                      const int* __restrict__ etp,
                                                      const int* __restrict__ row_ptr,
                                                      int* __restrict__ cursor,
                                                      unsigned* __restrict__ sorted) {
    int e = blockIdx.x * 256 + threadIdx.x;
    if (e >= N_EDGES) return;
    int d = dstp[e];
    int pos = atomicAdd(cursor + d, 1);
    sorted[row_ptr[d] + pos] = (unsigned)srcp[e] | ((unsigned)etp[e] << 16);
}

// ---------------- fused softmax + aggregate + bias + relu ----------------
// xw is column-permuted: position p holds col (p&7)*16 + (p>>3).
__device__ inline float2 ldxw(const __half* xw, unsigned p, int lane) {
    const __half2 h2 = *((const __half2*)xw + (((size_t)(p >> 16)) * N_NODES + (p & 0xffff)) * (F_DIM / 2) + lane);
    return make_float2(__half2float(h2.x), __half2float(h2.y));
}

__global__ __launch_bounds__(256) void agg_fused(const __half* __restrict__ xw,
                                                 const float* __restrict__ a_q,
                                                 const float* __restrict__ a_k,
                                                 const int* __restrict__ row_ptr,
                                                 const unsigned* __restrict__ sorted,
                                                 const float* __restrict__ bias,
                                                 float* __restrict__ out) {
    const int lane = threadIdx.x & 63;
    const int wave = threadIdx.x >> 6;
    const int d = blockIdx.x * 4 + wave;
    if (d >= N_NODES) return;
    const int beg = row_ptr[d], end = row_ptr[d + 1];
    const int cnt = end - beg;

    // this lane's two (permuted) columns
    const int p0 = lane * 2;
    const int c0 = (p0 & 7) * 16 + (p0 >> 3);
    const int c1 = c0 + 16;
    float2 acc = make_float2(bias[c0], bias[c1]);

    if (cnt <= 64) {
        unsigned p = 0;
        float l = -3.4e38f;
        if (lane < cnt) {
            p = sorted[beg + lane];
            int s = p & 0xffff, t = p >> 16;
            l = lrelu(a_q[t * N_NODES + d] + a_k[t * N_NODES + s]);
        }
        float m = l;
#pragma unroll
        for (int off = 32; off > 0; off >>= 1) m = fmaxf(m, __shfl_xor(m, off));
        float ex = (lane < cnt) ? __expf(l - m) : 0.f;
        float dsum = ex;
#pragma unroll
        for (int off = 32; off > 0; off >>= 1) dsum += __shfl_xor(dsum, off);
        float alpha = ex / (dsum + 1e-16f);

        int i = 0;
        for (; i + 4 <= cnt; i += 4) {
            unsigned p0e = __shfl(p, i), p1e = __shfl(p, i + 1);
            unsigned p2e = __shfl(p, i + 2), p3e = __shfl(p, i + 3);
            float a0 = __shfl(alpha, i), a1 = __shfl(alpha, i + 1);
            float a2 = __shfl(alpha, i + 2), a3 = __shfl(alpha, i + 3);
            float2 v0 = ldxw(xw, p0e, lane);
            float2 v1 = ldxw(xw, p1e, lane);
            float2 v2 = ldxw(xw, p2e, lane);
            float2 v3 = ldxw(xw, p3e, lane);
            acc.x = fmaf(a0, v0.x, acc.x); acc.y = fmaf(a0, v0.y, acc.y);
            acc.x = fmaf(a1, v1.x, acc.x); acc.y = fmaf(a1, v1.y, acc.y);
            acc.x = fmaf(a2, v2.x, acc.x); acc.y = fmaf(a2, v2.y, acc.y);
            acc.x = fmaf(a3, v3.x, acc.x); acc.y = fmaf(a3, v3.y, acc.y);
        }
        for (; i < cnt; ++i) {
            unsigned pi = __shfl(p, i);
            float ai = __shfl(alpha, i);
            float2 v = ldxw(xw, pi, lane);
            acc.x = fmaf(ai, v.x, acc.x);
            acc.y = fmaf(ai, v.y, acc.y);
        }
    } else {
        float m = -3.4e38f;
        for (int i = beg + lane; i < end; i += 64) {
            unsigned p = sorted[i];
            int s = p & 0xffff, t = p >> 16;
            m = fmaxf(m, lrelu(a_q[t * N_NODES + d] + a_k[t * N_NODES + s]));
        }
#pragma unroll
        for (int off = 32; off > 0; off >>= 1) m = fmaxf(m, __shfl_xor(m, off));
        float dsum = 0.f;
        for (int i = beg + lane; i < end; i += 64) {
            unsigned p = sorted[i];
            int s = p & 0xffff, t = p >> 16;
            dsum += __expf(lrelu(a_q[t * N_NODES + d] + a_k[t * N_NODES + s]) - m);
        }
#pragma unroll
        for (int off = 32; off > 0; off >>= 1) dsum += __shfl_xor(dsum, off);
        const float inv = 1.f / (dsum + 1e-16f);
        for (int i = beg; i < end; ++i) {
            unsigned p = sorted[i];
            int s = p & 0xffff, t = p >> 16;
            float alpha = __expf(lrelu(a_q[t * N_NODES + d] + a_k[t * N_NODES + s]) - m) * inv;
            float2 v = ldxw(xw, p, lane);
            acc.x = fmaf(alpha, v.x, acc.x);
            acc.y = fmaf(alpha, v.y, acc.y);
        }
    }
    out[(size_t)d * F_DIM + c0] = fmaxf(acc.x, 0.f);
    out[(size_t)d * F_DIM + c1] = fmaxf(acc.y, 0.f);
}

// ---------------- driver ----------------

extern "C" void kernel_launch(void* const* d_in, const int* in_sizes, int n_in,
                              void* d_out, int out_size, void* d_ws, size_t ws_size,
                              hipStream_t stream) {
    const float* x     = (const float*)d_in[0];
    const float* W     = (const float*)d_in[1];
    const float* att_q = (const float*)d_in[2];
    const float* att_k = (const float*)d_in[3];
    const float* bias  = (const float*)d_in[4];
    const int* ei      = (const int*)d_in[5];
    const int* etp     = (const int*)d_in[6];
    const int* srcp = ei;
    const int* dstp = ei + N_EDGES;
    float* out = (float*)d_out;
    char* ws   = (char*)d_ws;

    size_t off = 0;
    auto alloc = [&](size_t bytes) {
        void* p = ws + off;
        off = (off + bytes + 511) & ~(size_t)511;
        return p;
    };
    __half* xw       = (__half*)alloc((size_t)N_REL * N_NODES * F_DIM * sizeof(__half));
    float* a_q       = (float*)alloc((size_t)N_REL * N_NODES * sizeof(float));
    float* a_k       = (float*)alloc((size_t)N_REL * N_NODES * sizeof(float));
    int* cnt         = (int*)alloc((size_t)N_NODES * sizeof(int));
    int* row_ptr     = (int*)alloc(((size_t)N_NODES + 1) * sizeof(int));
    int* partial     = (int*)alloc(256 * sizeof(int));
    unsigned* sorted = (unsigned*)alloc((size_t)N_EDGES * sizeof(unsigned));
    short* Wh        = (short*)alloc((size_t)N_LAYERS * N_REL * F_DIM * F_DIM * sizeof(short));
    short* Wl        = (short*)alloc((size_t)N_LAYERS * N_REL * F_DIM * F_DIM * sizeof(short));
    short* Hh        = (short*)alloc((size_t)N_NODES * F_DIM * sizeof(short));
    short* Hl        = (short*)alloc((size_t)N_NODES * F_DIM * sizeof(short));

    prep_w<<<N_LAYERS * N_REL, 256, 0, stream>>>(W, Wh, Wl);
    hipMemsetAsync(cnt, 0, (size_t)N_NODES * 4, stream);
    count_kernel<<<(N_EDGES + 255) / 256, 256, 0, stream>>>(dstp, cnt);
    block_sum_kernel<<<NBLK_N, 256, 0, stream>>>(cnt, partial);
    scan_partials_kernel<<<1, 256, 0, stream>>>(partial, row_ptr);
    scan_block_kernel<<<NBLK_N, 256, 0, stream>>>(cnt, partial, row_ptr);
    hipMemsetAsync(cnt, 0, (size_t)N_NODES * 4, stream);
    scatter_kernel<<<(N_EDGES + 255) / 256, 256, 0, stream>>>(
        srcp, dstp, etp, row_ptr, cnt, sorted);

    const int grid_h = (N_NODES * F_DIM / 8 + 255) / 256;   // 3125
    const int grid_m = (N_NODES + GBM - 1) / GBM;           // 391
    for (int l = 0; l < N_LAYERS; ++l) {
        const float* H = (l == 0) ? x : out;
        prep_h<<<grid_h, 256, 0, stream>>>(H, Hh, Hl);
        gemm_xw<<<dim3(grid_m, N_REL / RGRP), 512, 0, stream>>>(
            Hh, Hl,
            Wh + (size_t)l * N_REL * F_DIM * F_DIM,
            Wl + (size_t)l * N_REL * F_DIM * F_DIM,
            att_q + l * F_DIM, att_k + l * F_DIM,
            xw, a_q, a_k);
        agg_fused<<<(N_NODES + 3) / 4, 256, 0, stream>>>(
            xw, a_q, a_k, row_ptr, sorted, bias + l * F_DIM, out);
    }
}